// Round 1
// baseline (135.415 us; speedup 1.0000x reference)
//
#include <hip/hip_runtime.h>
#include <math.h>

#define M_TOT 87296
#define INF_F 100000000.0f

// ws layout (floats): [0]=reg_sum [1]=reg_cnt [2]=neg_sum
__global__ void init_acc(float* acc) {
    if (threadIdx.x < 8) acc[threadIdx.x] = 0.0f;
}

__global__ __launch_bounds__(256) void main_kernel(
    const float* __restrict__ boxes,     // [4,64,4]
    const float* __restrict__ agn,       // [M_TOT]
    const float* __restrict__ reg_pred,  // [M_TOT,4]
    float* __restrict__ acc)
{
    __shared__ float sx1[256], sy1[256], sx2[256], sy2[256], scx[256], scy[256], sr2[256];
    const int t = threadIdx.x;
    {
        const float4 bx = ((const float4*)boxes)[t];
        sx1[t] = bx.x; sy1[t] = bx.y; sx2[t] = bx.z; sy2[t] = bx.w;
        scx[t] = (bx.x + bx.z) * 0.5f;
        scy[t] = (bx.y + bx.w) * 0.5f;
        float area = (bx.z - bx.x) * (bx.w - bx.y);
        // DELTA**2 * 2 computed in double then rounded to f32 (matches JAX scalar promotion)
        const double DELTA = (1.0 - 0.8) / (1.0 + 0.8);
        const float RADC = (float)(DELTA * DELTA * 2.0);
        sr2[t] = fmaxf(RADC * area, 16.0f);
    }
    __syncthreads();

    const int m = blockIdx.x * 256 + t;
    // level decode (blocks never straddle levels: boundaries are multiples of 256)
    int lev;
    if      (m < 65536) lev = 0;
    else if (m < 81920) lev = 1;
    else if (m < 86016) lev = 2;
    else if (m < 87040) lev = 3;
    else                lev = 4;
    const int   LB[5]    = {0, 65536, 81920, 86016, 87040};
    const int   locSh[5] = {14, 12, 10, 8, 6};
    const int   wSh[5]   = {7, 6, 5, 4, 3};
    const float SV[5]    = {8.f, 16.f, 32.f, 64.f, 128.f};
    const float LOv[5]   = {0.f, 64.f, 128.f, 256.f, 512.f};
    const float HIv[5]   = {80.f, 160.f, 320.f, 640.f, 10000000.f};

    const int r    = m - LB[lev];
    const int b    = r >> locSh[lev];
    const int p    = r & ((1 << locSh[lev]) - 1);
    const int gyid = p >> wSh[lev];
    const int gxid = p & ((1 << wSh[lev]) - 1);
    const float s    = SV[lev];
    const float half = s * 0.5f;
    const float gx = (float)gxid * s + half;
    const float gy = (float)gyid * s + half;
    const float lo = LOv[lev], hi = HIv[lev];

    float bestD = INF_F;   // masked min (d)
    int   bestN = 0;       // argmin, first-min semantics via strict <
    float minW  = INF_F;   // UNMASKED wdist2 min (for heatmap)

    const int base = b * 64;
    #pragma unroll 4
    for (int n = 0; n < 64; ++n) {
        const int i = base + n;
        const float x1 = sx1[i], y1 = sy1[i], x2 = sx2[i], y2 = sy2[i];
        const float l  = gx - x1;
        const float tt = gy - y1;
        const float rr = x2 - gx;
        const float bb = y2 - gy;
        const bool is_in = fminf(fminf(l, tt), fminf(rr, bb)) > 0.0f;

        const float cx = scx[i], cy = scy[i];
        // quantized center: int32 truncation semantics (centers >= 0)
        const float qx = truncf(cx / s) * s + half;
        const float qy = truncf(cy / s) * s + half;
        const float dx = gx - qx, dy = gy - qy;
        const bool is_peak = (dx * dx + dy * dy) == 0.0f;
        const bool c3 = (fabsf(dx) <= s) && (fabsf(dy) <= s) && is_in;

        // crit computed as (l+r),(t+b) like the reference (not x2-x1)
        const float wsum = l + rr;
        const float hsum = tt + bb;
        const float crit = sqrtf(wsum * wsum + hsum * hsum) * 0.5f;
        const bool cared = (crit >= lo) && (crit <= hi);
        const bool msk = c3 && cared;

        const float ddx = gx - cx, ddy = gy - cy;
        const float dist2 = is_peak ? 0.0f : (ddx * ddx + ddy * ddy);
        const float w2 = dist2 / sr2[i];
        minW = fminf(minW, w2);
        const float d = msk ? w2 : INF_F;
        if (d < bestD) { bestD = d; bestN = n; }
    }

    // heatmap -> negative focal weight
    float hmv = expf(-minW);
    if (hmv < 1e-4f) hmv = 0.0f;
    const float neg_w = powf(1.0f - hmv, 4.0f);

    const float z = agn[m];
    float pr = 1.0f / (1.0f + expf(-z));
    pr = fminf(fmaxf(pr, 1e-4f), 1.0f - 1e-4f);
    float neg_term = 0.0f;
    if (pr < 0.85f) neg_term = logf(1.0f - pr) * powf(pr, 2.0f) * neg_w;

    float reg_term = 0.0f, reg_val = 0.0f;
    if (bestD < INF_F) {
        reg_val = 1.0f;
        const int i = base + bestN;
        const float tl = (gx - sx1[i]) / s;
        const float tt2 = (gy - sy1[i]) / s;
        const float tr = (sx2[i] - gx) / s;
        const float tb = (sy2[i] - gy) / s;
        const float4 pv = ((const float4*)reg_pred)[m];
        const float pl = pv.x, pt = pv.y, prr = pv.z, pb = pv.w;
        const float target_area = (tl + tr) * (tt2 + tb);
        const float pred_area   = (pl + prr) * (pt + pb);
        const float w_i = fminf(pl, tl) + fminf(prr, tr);
        const float g_w = fmaxf(pl, tl) + fmaxf(prr, tr);
        const float h_i = fminf(pb, tb) + fminf(pt, tt2);
        const float g_h = fmaxf(pb, tb) + fmaxf(pt, tt2);
        const float ac    = g_w * g_h + 1e-7f;
        const float inter = w_i * h_i;
        const float uni   = target_area + pred_area - inter;
        const float ious  = (inter + 1.0f) / (uni + 1.0f);
        const float gious = ious - (ac - uni) / ac;
        reg_term = 1.0f - gious;
    }

    // wave(64) shuffle reduction, then one atomic per wave
    for (int off = 32; off; off >>= 1) {
        reg_term += __shfl_down(reg_term, off);
        reg_val  += __shfl_down(reg_val,  off);
        neg_term += __shfl_down(neg_term, off);
    }
    if ((t & 63) == 0) {
        atomicAdd(&acc[0], reg_term);
        atomicAdd(&acc[1], reg_val);
        atomicAdd(&acc[2], neg_term);
    }
}

__global__ __launch_bounds__(256) void pos_finalize(
    const float* __restrict__ boxes,
    const float* __restrict__ agn,
    const float* __restrict__ acc,
    float* __restrict__ out)
{
    const int t = threadIdx.x;
    const int   BAS[5] = {0, 65536, 81920, 86016, 87040};
    const int   LOC[5] = {16384, 4096, 1024, 256, 64};
    const int   WW[5]  = {128, 64, 32, 16, 8};
    const float ST[5]  = {8.f, 16.f, 32.f, 64.f, 128.f};
    const float LOv[5] = {0.f, 64.f, 128.f, 256.f, 512.f};
    const float HIv[5] = {80.f, 160.f, 320.f, 640.f, 10000000.f};

    float psum = 0.0f, pcnt = 0.0f;
    // j indexes [B,N,L] flattened: 4*64*5 = 1280
    for (int j = t; j < 1280; j += 256) {
        const int lev = j % 5;
        const int bn  = j / 5;            // b*64 + n
        const int b   = bn >> 6;
        const float4 bx = ((const float4*)boxes)[bn];
        const float cx = (bx.x + bx.z) * 0.5f;
        const float cy = (bx.y + bx.w) * 0.5f;
        const int cix = (int)(cx / ST[lev]);
        const int ciy = (int)(cy / ST[lev]);
        int pos = BAS[lev] + b * LOC[lev] + ciy * WW[lev] + cix;
        pos = min(max(pos, 0), M_TOT - 1);
        // mask depends ONLY on crit (no spatial bounds), matching reference
        const float dx = bx.z - bx.x, dy = bx.w - bx.y;
        const float crit = sqrtf(dx * dx + dy * dy) * 0.5f;
        const bool msk = (crit >= LOv[lev]) && (crit <= HIv[lev]);
        const float z = agn[pos];
        float pp = 1.0f / (1.0f + expf(-z));
        pp = fminf(fmaxf(pp, 1e-4f), 1.0f - 1e-4f);
        if (msk) {
            psum += logf(pp) * powf(1.0f - pp, 2.0f);
            pcnt += 1.0f;
        }
    }

    __shared__ float sps[4], spc[4];
    for (int off = 32; off; off >>= 1) {
        psum += __shfl_down(psum, off);
        pcnt += __shfl_down(pcnt, off);
    }
    if ((t & 63) == 0) { sps[t >> 6] = psum; spc[t >> 6] = pcnt; }
    __syncthreads();
    if (t == 0) {
        const float PS = sps[0] + sps[1] + sps[2] + sps[3];
        const float PC = spc[0] + spc[1] + spc[2] + spc[3];
        const float num_pos  = fmaxf(PC, 1.0f);
        const float reg_norm = fmaxf(acc[1], 1.0f);
        out[0] = acc[0] / reg_norm;                       // REG_WEIGHT = 1
        out[1] = 0.5f * (0.25f * -PS) / num_pos;          // POS_W * ALPHA
        out[2] = 0.5f * (0.75f * -acc[2]) / num_pos;      // NEG_W * (1-ALPHA)
    }
}

extern "C" void kernel_launch(void* const* d_in, const int* in_sizes, int n_in,
                              void* d_out, int out_size, void* d_ws, size_t ws_size,
                              hipStream_t stream) {
    const float* boxes    = (const float*)d_in[0];   // [4,64,4] f32
    // d_in[1] = gt_classes (unused)
    const float* agn      = (const float*)d_in[2];   // [87296] f32
    const float* reg_pred = (const float*)d_in[3];   // [87296,4] f32
    float* out = (float*)d_out;
    float* acc = (float*)d_ws;

    init_acc<<<1, 64, 0, stream>>>(acc);
    main_kernel<<<M_TOT / 256, 256, 0, stream>>>(boxes, agn, reg_pred, acc);
    pos_finalize<<<1, 256, 0, stream>>>(boxes, agn, acc, out);
}

// Round 2
// 82.203 us; speedup vs baseline: 1.6473x; 1.6473x over previous
//
#include <hip/hip_runtime.h>
#include <math.h>

#define M_TOT 87296
#define NB    1364          // main-kernel blocks: 64 locations x 4 subs = 256 threads
#define INF_F 100000000.0f

// d_ws layout (floats): partial[0..NB)=reg_sum, [NB..2NB)=reg_cnt, [2NB..3NB)=neg_sum

__global__ __launch_bounds__(256, 4) void main_kernel(
    const float* __restrict__ boxes,     // [4,64,4]
    const float* __restrict__ agn,       // [M_TOT]
    const float* __restrict__ reg_pred,  // [M_TOT,4]
    float* __restrict__ partial)
{
    __shared__ float4 sA[64];   // x1,y1,x2,y2
    __shared__ float4 sB[64];   // qx,qy,cx,cy
    __shared__ float  sC[64];   // 1/radius2
    __shared__ float  sRed[12]; // 4 waves x 3 partials

    const int t     = threadIdx.x;
    const int blk   = blockIdx.x;
    const int mbase = blk * 64;

    // every block is single-level AND single-image (all chunk sizes are multiples of 64)
    int lev;
    if      (mbase < 65536) lev = 0;
    else if (mbase < 81920) lev = 1;
    else if (mbase < 86016) lev = 2;
    else if (mbase < 87040) lev = 3;
    else                    lev = 4;

    const int   LB_[5]   = {0, 65536, 81920, 86016, 87040};
    const int   locSh[5] = {14, 12, 10, 8, 6};
    const int   wSh[5]   = {7, 6, 5, 4, 3};
    const float SV[5]    = {8.f, 16.f, 32.f, 64.f, 128.f};
    const float LOv[5]   = {0.f, 64.f, 128.f, 256.f, 512.f};
    const float HIv[5]   = {80.f, 160.f, 320.f, 640.f, 10000000.f};

    const float s     = SV[lev];
    const float inv_s = 1.0f / s;      // s is a power of 2: exact reciprocal
    const float half  = 0.5f * s;
    const int   bimg  = (mbase - LB_[lev]) >> locSh[lev];

    if (t < 64) {
        const float4 bx = ((const float4*)boxes)[bimg * 64 + t];
        const float cx = (bx.x + bx.z) * 0.5f;
        const float cy = (bx.y + bx.w) * 0.5f;
        // *inv_s is bit-identical to /s (power of 2); truncf == int32 cast (centers >= 0)
        const float qx = truncf(cx * inv_s) * s + half;
        const float qy = truncf(cy * inv_s) * s + half;
        const float area = (bx.z - bx.x) * (bx.w - bx.y);
        const double DELTA = (1.0 - 0.8) / (1.0 + 0.8);
        const float RADC = (float)(DELTA * DELTA * 2.0);
        const float r2 = fmaxf(RADC * area, 16.0f);
        sA[t] = bx;
        sB[t] = make_float4(qx, qy, cx, cy);
        sC[t] = 1.0f / r2;
    }
    __syncthreads();

    const int   mloc = mbase + (t >> 2);
    const int   sub  = t & 3;
    const int   p    = (mloc - LB_[lev]) & ((1 << locSh[lev]) - 1);
    const float gx   = (float)(p & ((1 << wSh[lev]) - 1)) * s + half;
    const float gy   = (float)(p >> wSh[lev]) * s + half;
    const float lo   = LOv[lev], hi = HIv[lev];

    float minW = INF_F;
    unsigned long long bestKey = ~0ULL;

    #pragma unroll
    for (int k = 0; k < 16; ++k) {
        const int n = k * 4 + sub;          // lanes of a wave read 4 consecutive slots
        const float4 A  = sA[n];
        const float4 Bv = sB[n];
        const float  ir2 = sC[n];

        const float l  = gx - A.x;
        const float tt = gy - A.y;
        const float rr = A.z - gx;
        const float bb = A.w - gy;
        const bool is_in = fminf(fminf(l, tt), fminf(rr, bb)) > 0.0f;

        const float dx = gx - Bv.x, dy = gy - Bv.y;
        const bool is_peak = (dx * dx + dy * dy) == 0.0f;
        const bool c3 = (fabsf(dx) <= s) && (fabsf(dy) <= s) && is_in;

        const float wsum = l + rr, hsum = tt + bb;      // same FP order as reference
        const float crit = sqrtf(wsum * wsum + hsum * hsum) * 0.5f;
        const bool msk = c3 && (crit >= lo) && (crit <= hi);

        const float ddx = gx - Bv.z, ddy = gy - Bv.w;
        const float dist2 = is_peak ? 0.0f : (ddx * ddx + ddy * ddy);
        const float w2 = dist2 * ir2;
        minW = fminf(minW, w2);

        const float d = msk ? w2 : INF_F;
        // nonneg float bits are order-preserving; key min == (min d, then min n)
        const unsigned long long key =
            ((unsigned long long)__float_as_uint(d) << 6) | (unsigned)n;
        bestKey = key < bestKey ? key : bestKey;
    }

    // combine the 4 sub-lanes handling the same location
    {
        unsigned long long o = __shfl_xor(bestKey, 1);
        bestKey = o < bestKey ? o : bestKey;
        o = __shfl_xor(bestKey, 2);
        bestKey = o < bestKey ? o : bestKey;
        float w = __shfl_xor(minW, 1); minW = fminf(minW, w);
        w = __shfl_xor(minW, 2);       minW = fminf(minW, w);
    }

    float reg_term = 0.0f, reg_val = 0.0f, neg_term = 0.0f;
    if (sub == 0) {
        float hmv = expf(-minW);
        if (hmv < 1e-4f) hmv = 0.0f;
        const float neg_w = powf(1.0f - hmv, 4.0f);

        const float z = agn[mloc];
        float pr = 1.0f / (1.0f + expf(-z));
        pr = fminf(fmaxf(pr, 1e-4f), 1.0f - 1e-4f);
        if (pr < 0.85f) neg_term = logf(1.0f - pr) * powf(pr, 2.0f) * neg_w;

        const unsigned dbits = (unsigned)(bestKey >> 6);
        if (dbits < __float_as_uint(INF_F)) {
            reg_val = 1.0f;
            const int n = (int)(bestKey & 63);
            const float4 A = sA[n];
            const float tl  = (gx - A.x) * inv_s;   // bit-exact vs /s
            const float tt2 = (gy - A.y) * inv_s;
            const float tr  = (A.z - gx) * inv_s;
            const float tb  = (A.w - gy) * inv_s;
            const float4 pv = ((const float4*)reg_pred)[mloc];
            const float pl = pv.x, pt = pv.y, prr = pv.z, pb = pv.w;
            const float target_area = (tl + tr) * (tt2 + tb);
            const float pred_area   = (pl + prr) * (pt + pb);
            const float w_i = fminf(pl, tl) + fminf(prr, tr);
            const float g_w = fmaxf(pl, tl) + fmaxf(prr, tr);
            const float h_i = fminf(pb, tb) + fminf(pt, tt2);
            const float g_h = fmaxf(pb, tb) + fmaxf(pt, tt2);
            const float ac    = g_w * g_h + 1e-7f;
            const float inter = w_i * h_i;
            const float uni   = target_area + pred_area - inter;
            const float ious  = (inter + 1.0f) / (uni + 1.0f);
            const float gious = ious - (ac - uni) / ac;
            reg_term = 1.0f - gious;
        }
    }

    // wave(64) reduction, then 4-wave LDS reduce, one partial row per block
    for (int off = 32; off; off >>= 1) {
        reg_term += __shfl_down(reg_term, off);
        reg_val  += __shfl_down(reg_val,  off);
        neg_term += __shfl_down(neg_term, off);
    }
    if ((t & 63) == 0) {
        const int w = t >> 6;
        sRed[w * 3 + 0] = reg_term;
        sRed[w * 3 + 1] = reg_val;
        sRed[w * 3 + 2] = neg_term;
    }
    __syncthreads();
    if (t == 0) {
        partial[blk]          = sRed[0] + sRed[3] + sRed[6] + sRed[9];
        partial[NB + blk]     = sRed[1] + sRed[4] + sRed[7] + sRed[10];
        partial[2 * NB + blk] = sRed[2] + sRed[5] + sRed[8] + sRed[11];
    }
}

__global__ __launch_bounds__(256) void finalize(
    const float* __restrict__ boxes,
    const float* __restrict__ agn,
    const float* __restrict__ partial,
    float* __restrict__ out)
{
    const int t = threadIdx.x;

    float racc = 0.0f, cacc = 0.0f, nacc = 0.0f;
    for (int j = t; j < NB; j += 256) {
        racc += partial[j];
        cacc += partial[NB + j];
        nacc += partial[2 * NB + j];
    }

    const int   BAS[5] = {0, 65536, 81920, 86016, 87040};
    const int   LOC[5] = {16384, 4096, 1024, 256, 64};
    const int   WW[5]  = {128, 64, 32, 16, 8};
    const float ST[5]  = {8.f, 16.f, 32.f, 64.f, 128.f};
    const float LOv[5] = {0.f, 64.f, 128.f, 256.f, 512.f};
    const float HIv[5] = {80.f, 160.f, 320.f, 640.f, 10000000.f};

    float psum = 0.0f, pcnt = 0.0f;
    for (int j = t; j < 1280; j += 256) {   // [B,N,L] flattened, L fastest
        const int lev = j % 5;
        const int bn  = j / 5;
        const int b   = bn >> 6;
        const float4 bx = ((const float4*)boxes)[bn];
        const float cx = (bx.x + bx.z) * 0.5f;
        const float cy = (bx.y + bx.w) * 0.5f;
        const int cix = (int)(cx / ST[lev]);
        const int ciy = (int)(cy / ST[lev]);
        int pos = BAS[lev] + b * LOC[lev] + ciy * WW[lev] + cix;
        pos = min(max(pos, 0), M_TOT - 1);
        const float dx = bx.z - bx.x, dy = bx.w - bx.y;
        const float crit = sqrtf(dx * dx + dy * dy) * 0.5f;
        const bool msk = (crit >= LOv[lev]) && (crit <= HIv[lev]);
        const float z = agn[pos];
        float pp = 1.0f / (1.0f + expf(-z));
        pp = fminf(fmaxf(pp, 1e-4f), 1.0f - 1e-4f);
        if (msk) {
            psum += logf(pp) * powf(1.0f - pp, 2.0f);
            pcnt += 1.0f;
        }
    }

    for (int off = 32; off; off >>= 1) {
        racc += __shfl_down(racc, off);
        cacc += __shfl_down(cacc, off);
        nacc += __shfl_down(nacc, off);
        psum += __shfl_down(psum, off);
        pcnt += __shfl_down(pcnt, off);
    }
    __shared__ float sr[4][5];
    if ((t & 63) == 0) {
        const int w = t >> 6;
        sr[w][0] = racc; sr[w][1] = cacc; sr[w][2] = nacc;
        sr[w][3] = psum; sr[w][4] = pcnt;
    }
    __syncthreads();
    if (t == 0) {
        const float RS = sr[0][0] + sr[1][0] + sr[2][0] + sr[3][0];
        const float RC = sr[0][1] + sr[1][1] + sr[2][1] + sr[3][1];
        const float NS = sr[0][2] + sr[1][2] + sr[2][2] + sr[3][2];
        const float PS = sr[0][3] + sr[1][3] + sr[2][3] + sr[3][3];
        const float PC = sr[0][4] + sr[1][4] + sr[2][4] + sr[3][4];
        const float num_pos  = fmaxf(PC, 1.0f);
        const float reg_norm = fmaxf(RC, 1.0f);
        out[0] = RS / reg_norm;                     // REG_WEIGHT = 1
        out[1] = 0.5f * (0.25f * -PS) / num_pos;    // POS_W * ALPHA
        out[2] = 0.5f * (0.75f * -NS) / num_pos;    // NEG_W * (1-ALPHA)
    }
}

extern "C" void kernel_launch(void* const* d_in, const int* in_sizes, int n_in,
                              void* d_out, int out_size, void* d_ws, size_t ws_size,
                              hipStream_t stream) {
    const float* boxes    = (const float*)d_in[0];   // [4,64,4] f32
    // d_in[1] = gt_classes (unused)
    const float* agn      = (const float*)d_in[2];   // [87296] f32
    const float* reg_pred = (const float*)d_in[3];   // [87296,4] f32
    float* out     = (float*)d_out;
    float* partial = (float*)d_ws;                   // 3*NB floats

    main_kernel<<<NB, 256, 0, stream>>>(boxes, agn, reg_pred, partial);
    finalize<<<1, 256, 0, stream>>>(boxes, agn, partial, out);
}